// Round 1
// 1550.656 us; speedup vs baseline: 1.0787x; 1.0787x over previous
//
#include <hip/hip_runtime.h>
#include <hip/hip_bf16.h>
#include <hip/hip_fp16.h>

// Problem: bidirectional LSTM over 512 sequential steps (batch=12 lanes), then per-doc scoring.
// K0a/K0b: fp32->fp16 convert+pad, vectorized x4 (K 5400->5408). K1: MFMA fp16 GEMM (6144x5408)@(5408x2048)+bias -> G(f16),
//          m97 structure: global_load_lds width=16, linear LDS, 2 barriers/K-step.
// K2: 24 blocks (lane,dir), Whh fp16 resident in VGPRs(232 u32)+LDS(48KB row-major tail), v_dot2_f32_f16.
//     2 barriers/step (removed redundant barrier), nonlinearities hoisted pre-barrier.
// K3: per-doc epilogue fp32, exact argmax/argsort-tie semantics.
// ws: [0,66453504) x_h (later aliased by H 12.6MB) | [66453504) W_h 22.2MB | [88604672) G 25.2MB. total 113,770,496 B.

typedef _Float16 h8 __attribute__((ext_vector_type(8)));
typedef _Float16 h2 __attribute__((ext_vector_type(2)));
typedef _Float16 h4 __attribute__((ext_vector_type(4)));
typedef float f4 __attribute__((ext_vector_type(4)));

#define SEQ 512
#define NL 12
#define KIN 5400
#define KP 5408
#define NG 2048
#define MROWS 6144

__device__ __forceinline__ unsigned int pk2(float a, float b){
  h2 v; v[0] = (_Float16)a; v[1] = (_Float16)b;
  return __builtin_bit_cast(unsigned int, v);
}
__device__ __forceinline__ float dot2u(unsigned int h, unsigned int w, float acc){
  return __builtin_amdgcn_fdot2(__builtin_bit_cast(h2, h), __builtin_bit_cast(h2, w), acc, false);
}
__device__ __forceinline__ float sigm(float x){ return 1.f/(1.f + __expf(-x)); }
__device__ __forceinline__ float tanhx(float x){ return 1.f - 2.f/(__expf(2.f*x) + 1.f); }

__device__ __forceinline__ void gload16(const void* g, void* l){
  __builtin_amdgcn_global_load_lds((const __attribute__((address_space(1))) void*)g,
                                   (__attribute__((address_space(3))) void*)l, 16, 0, 0);
}

// ---------------- K0a: convert x (6144x5400 f32) -> xh (6144x5408 f16, zero pad), 4 elems/thread ----------------
__global__ void cvt_x(const float* __restrict__ x, _Float16* __restrict__ xh){
  int idx = blockIdx.x * 256 + threadIdx.x;     // < 6144*1352
  int row = idx / 1352, c4 = idx - row * 1352;
  h4 o = {};
  if (c4 < 1350){
    f4 v = *(const f4*)(x + (size_t)row * KIN + c4 * 4);
    o[0] = (_Float16)v.x; o[1] = (_Float16)v.y; o[2] = (_Float16)v.z; o[3] = (_Float16)v.w;
  }
  *(h4*)(xh + (size_t)row * KP + c4 * 4) = o;
}

// ---------------- K0b: convert [Wih_f; Wih_b] -> wh (2048x5408 f16, zero pad), 4 elems/thread ----------------
__global__ void cvt_w(const float* __restrict__ wf, const float* __restrict__ wb,
                      _Float16* __restrict__ wh){
  int idx = blockIdx.x * 256 + threadIdx.x;     // < 2048*1352
  int row = idx / 1352, c4 = idx - row * 1352;
  h4 o = {};
  if (c4 < 1350){
    const float* src = (row < 1024) ? (wf + (size_t)row * KIN) : (wb + (size_t)(row - 1024) * KIN);
    f4 v = *(const f4*)(src + c4 * 4);
    o[0] = (_Float16)v.x; o[1] = (_Float16)v.y; o[2] = (_Float16)v.z; o[3] = (_Float16)v.w;
  }
  *(h4*)(wh + (size_t)row * KP + c4 * 4) = o;
}

// ---------------- K1: G = xh @ wh^T + bias, fp16 MFMA, 128x128 tiles, global_load_lds staging ----------------
__global__ __launch_bounds__(256) void gemm_in(
    const _Float16* __restrict__ A, const _Float16* __restrict__ B, _Float16* __restrict__ G,
    const float* __restrict__ bif, const float* __restrict__ bhf,
    const float* __restrict__ bib, const float* __restrict__ bhb){
  // linear LDS tiles 128 rows x 32 k f16 (64 B/row) - dest of global_load_lds (must be linear)
  __shared__ _Float16 As[128 * 32];
  __shared__ _Float16 Bs[128 * 32];
  int tid = threadIdx.x;
  int bm = blockIdx.x % 48, bn = blockIdx.x / 48;
  int wid = tid >> 6, ln = tid & 63;
  int wm = wid & 1, wn = wid >> 1;
  int l15 = ln & 15, q = ln >> 4;
  // staging map: instr r (0/1), wave wid, lane ln -> row = r*64 + wid*16 + (ln>>2), col f16 = (ln&3)*8
  // LDS dest (HW): base + ln*16 bytes, base = r*4096 + wid*1024 (wave-uniform)
  int srow = wid * 16 + (ln >> 2);
  int scol = (ln & 3) * 8;
  const _Float16* a0 = A + (size_t)(bm * 128 + srow) * KP + scol;
  const _Float16* a1 = a0 + (size_t)64 * KP;
  const _Float16* b0 = B + (size_t)(bn * 128 + srow) * KP + scol;
  const _Float16* b1 = b0 + (size_t)64 * KP;
  char* AsB = (char*)As + wid * 1024;
  char* BsB = (char*)Bs + wid * 1024;
  f4 acc[4][4] = {};
  for (int kk = 0; kk < 169; ++kk){
    int k0 = kk * 32;
    gload16(a0 + k0, AsB);
    gload16(a1 + k0, AsB + 4096);
    gload16(b0 + k0, BsB);
    gload16(b1 + k0, BsB + 4096);
    __syncthreads();                 // drains vmcnt -> tiles in LDS
    h8 af[4], bfr[4];
    #pragma unroll
    for (int mt = 0; mt < 4; ++mt)
      af[mt] = *(const h8*)(As + (wm*64 + mt*16 + l15)*32 + q*8);
    #pragma unroll
    for (int nt = 0; nt < 4; ++nt)
      bfr[nt] = *(const h8*)(Bs + (wn*64 + nt*16 + l15)*32 + q*8);
    #pragma unroll
    for (int mt = 0; mt < 4; ++mt)
      #pragma unroll
      for (int nt = 0; nt < 4; ++nt)
        acc[mt][nt] = __builtin_amdgcn_mfma_f32_16x16x32_f16(af[mt], bfr[nt], acc[mt][nt], 0, 0, 0);
    __syncthreads();                 // all reads done before next overwrite
  }
  float bias[4];
  #pragma unroll
  for (int nt = 0; nt < 4; ++nt){
    int col = bn*128 + wn*64 + nt*16 + l15;
    bias[nt] = (col < 1024) ? (bif[col] + bhf[col]) : (bib[col-1024] + bhb[col-1024]);
  }
  #pragma unroll
  for (int mt = 0; mt < 4; ++mt)
    #pragma unroll
    for (int nt = 0; nt < 4; ++nt)
      #pragma unroll
      for (int r = 0; r < 4; ++r){
        int row = bm*128 + wm*64 + mt*16 + q*4 + r;   // C/D: row = quad*4+reg
        int col = bn*128 + wn*64 + nt*16 + l15;       //      col = lane&15
        G[(size_t)row * NG + col] = (_Float16)(acc[mt][nt][r] + bias[nt]);
      }
}

// ---------------- K2: recurrence. 24 blocks = (dir,lane). 512 thr, 2 gate rows each. ----------------
// gate layout [i(0:256) f(256:512) g(512:768) o(768:1024)]; thread t: rows t and t+512.
// t<256 owns (i_t, g_t); t+256 owns (f_t, o_t) -> pair exchange via LDS.
// Whh f16: u32-chunks 0..115 in VGPRs (wa/wb, 232 regs), chunks 116..127 in LDS tailT (48 KB, row-major).
// 2 barriers/step; sig(f)/sig(o)/sig(i)/tanh(g) computed pre-barrier by owning threads.
__global__ __launch_bounds__(512, 2) void lstm_rec(
    const float* __restrict__ Whhf, const float* __restrict__ Whhb,
    const _Float16* __restrict__ G, float* __restrict__ Hout){
  __shared__ unsigned int tailT[1024][12];   // 48 KB; tailT[row][c] = f16x2 chunk (116+c) of gate row
  __shared__ unsigned int hlds[128];         // h as 256 f16
  __shared__ float fg[256], og[256];         // hold sig(f), sig(o)
  int b = blockIdx.x;
  int dir = b / 12, lane = b - dir * 12;
  int t = threadIdx.x;
  const float* Whh = dir ? Whhb : Whhf;
  int r0 = t, r1 = t + 512;
  unsigned int wa[116], wb[116];
  #pragma unroll
  for (int c = 0; c < 128; ++c){
    float2 v0 = *(const float2*)(Whh + (size_t)r0 * 256 + 2*c);
    float2 v1 = *(const float2*)(Whh + (size_t)r1 * 256 + 2*c);
    unsigned int u0 = pk2(v0.x, v0.y);
    unsigned int u1 = pk2(v1.x, v1.y);
    if (c < 116){ wa[c] = u0; wb[c] = u1; }
    else { tailT[r0][c - 116] = u0; tailT[r1][c - 116] = u1; }
  }
  if (t < 128) hlds[t] = 0u;
  float cst = 0.f;
  __syncthreads();
  for (int it = 0; it < SEQ; ++it){
    int s = dir ? (SEQ - 1 - it) : it;
    const _Float16* gp = G + (size_t)(s*NL + lane) * NG + dir * 1024;
    float ga = (float)gp[r0];      // load early, used at end (overlaps dots)
    float gb = (float)gp[r1];
    float acc0 = 0.f, acc1 = 0.f;
    #pragma unroll
    for (int c4 = 0; c4 < 29; ++c4){
      uint4 hq = *(const uint4*)&hlds[c4*4];
      unsigned int ha[4] = {hq.x, hq.y, hq.z, hq.w};
      #pragma unroll
      for (int j = 0; j < 4; ++j){
        acc0 = dot2u(ha[j], wa[c4*4 + j], acc0);
        acc1 = dot2u(ha[j], wb[c4*4 + j], acc1);
      }
    }
    #pragma unroll
    for (int c4 = 0; c4 < 3; ++c4){
      uint4 hq = *(const uint4*)&hlds[116 + c4*4];
      uint4 wqa = *(const uint4*)&tailT[r0][c4*4];
      uint4 wqb = *(const uint4*)&tailT[r1][c4*4];
      unsigned int ha[4] = {hq.x, hq.y, hq.z, hq.w};
      unsigned int qa[4] = {wqa.x, wqa.y, wqa.z, wqa.w};
      unsigned int qb[4] = {wqb.x, wqb.y, wqb.z, wqb.w};
      #pragma unroll
      for (int j = 0; j < 4; ++j){
        acc0 = dot2u(ha[j], qa[j], acc0);
        acc1 = dot2u(ha[j], qb[j], acc1);
      }
    }
    acc0 += ga; acc1 += gb;
    // pre-barrier nonlinearities (all 8 waves busy; shortens post-barrier chain)
    float si = 0.f, tg = 0.f;
    if (t < 256){ si = sigm(acc0); tg = tanhx(acc1); }
    else { fg[t - 256] = sigm(acc0); og[t - 256] = sigm(acc1); }
    __syncthreads();                       // gates visible; also orders hlds reads before write
    if (t < 256){
      cst = fg[t]*cst + si*tg;
      float hv = og[t]*tanhx(cst);
      ((_Float16*)hlds)[t] = (_Float16)hv;
      Hout[(size_t)(s*NL + lane)*512 + dir*256 + t] = hv;
    }
    __syncthreads();                       // new h visible before next dots
  }
}

// ---------------- K3: per-doc epilogue ----------------
__global__ __launch_bounds__(256) void epilogue(
    const float* __restrict__ H, const float* __restrict__ encW, const float* __restrict__ encB,
    const float* __restrict__ wfcW, const float* __restrict__ wfcB,
    const float* __restrict__ fcW, const float* __restrict__ fcB, float* __restrict__ out){
  __shared__ float B0[12][516];   // +4 pad -> conflict-free row access
  __shared__ float B1[12][516];
  __shared__ float encl[12][52];
  __shared__ float part[12][16];
  __shared__ float av[12], bv[12], nrm[12], simv[12], rsv[12], docv[12];
  __shared__ float Wm[12][12];
  __shared__ int corei;
  int d = blockIdx.x, t = threadIdx.x;
  const float* Hd = H + (size_t)d * NL * 512;
  for (int idx = t; idx < NL * 128; idx += 256){
    int i = idx >> 7, h4i = (idx & 127) * 4;
    *(f4*)(&B0[i][h4i]) = *(const f4*)(Hd + i*512 + h4i);
  }
  __syncthreads();
  // enc = leaky_relu(H @ enc_W.T + enc_b)
  for (int idx = t; idx < 600; idx += 256){
    int i = idx % 12, e = idx / 12;
    float s = encB[e];
    const float* w = encW + e * 512;
    for (int h = 0; h < 512; ++h) s += B0[i][h] * w[h];
    encl[i][e] = (s >= 0.f) ? s : 0.01f * s;
  }
  __syncthreads();
  if (t < 12){
    float sa = 0.f, sb = 0.f;
    for (int e = 0; e < 50; ++e){ sa += encl[t][e]*wfcW[e]; sb += encl[t][e]*wfcW[50 + e]; }
    av[t] = sa; bv[t] = sb;
  }
  __syncthreads();
  if (t < 192){                    // ||H_i||^2 partials
    int i = t >> 4, sl = t & 15;
    float s = 0.f;
    for (int h = sl*32; h < sl*32 + 32; ++h){ float v = B0[i][h]; s += v*v; }
    part[i][sl] = s;
  }
  if (t == 192){                   // core = first argmax of rowsum
    float wbv = wfcB[0];
    float best = -1e30f; int bi = 0;
    for (int i = 0; i < 12; ++i){
      float rs = 0.f;
      for (int j = 0; j < 12; ++j) if (j != i) rs += av[i] + bv[j] + wbv;
      if (rs > best){ best = rs; bi = i; }
    }
    corei = bi;
  }
  __syncthreads();
  if (t < 12){
    float s = 0.f; for (int l = 0; l < 16; ++l) s += part[t][l];
    nrm[t] = sqrtf(s) + 1e-12f;
  }
  __syncthreads();
  if (t < 192){                    // dot(H_i, H_core) partials
    int i = t >> 4, sl = t & 15, cc = corei;
    float s = 0.f;
    for (int h = sl*32; h < sl*32 + 32; ++h) s += B0[i][h] * B0[cc][h];
    part[i][sl] = s;
  }
  __syncthreads();
  if (t < 12){
    float s = 0.f; for (int l = 0; l < 16; ++l) s += part[t][l];
    simv[t] = s / (nrm[t] * nrm[corei]);
  }
  __syncthreads();
  if (t < 12){                     // stable-argsort rank of -sim
    int rk = 0; float st = simv[t];
    for (int j = 0; j < 12; ++j){
      float sj = simv[j];
      rk += (sj > st) || (sj == st && j < t);
    }
    rsv[t] = 1.f - (float)rk / 12.f;
  }
  __syncthreads();
  if (t < 144){
    int i = t / 12, j = t - (t / 12) * 12;
    Wm[i][j] = (i == j) ? 0.f : (av[i] + bv[j] + wfcB[0]) * rsv[i];
  }
  __syncthreads();
  for (int h = t; h < 512; h += 256){     // emb iter 1: B0 -> B1
    float e[12];
    #pragma unroll
    for (int j = 0; j < 12; ++j) e[j] = B0[j][h];
    #pragma unroll
    for (int i = 0; i < 12; ++i){
      float s = e[i];
      #pragma unroll
      for (int j = 0; j < 12; ++j) s += Wm[i][j] * e[j];
      B1[i][h] = s;
    }
  }
  __syncthreads();
  for (int h = t; h < 512; h += 256){     // emb iter 2: B1 -> B0
    float e[12];
    #pragma unroll
    for (int j = 0; j < 12; ++j) e[j] = B1[j][h];
    #pragma unroll
    for (int i = 0; i < 12; ++i){
      float s = e[i];
      #pragma unroll
      for (int j = 0; j < 12; ++j) s += Wm[i][j] * e[j];
      B0[i][h] = s;
    }
  }
  __syncthreads();
  if (t < 192){
    int i = t >> 4, sl = t & 15;
    float s = 0.f;
    for (int h = sl*32; h < sl*32 + 32; ++h) s += B0[i][h];
    part[i][sl] = s;
  }
  __syncthreads();
  if (t < 12){
    float s = 0.f; for (int l = 0; l < 16; ++l) s += part[t][l];
    docv[t] = s / 512.f;
  }
  __syncthreads();
  if (t < 2){
    float s = fcB[t];
    for (int i = 0; i < 12; ++i) s += docv[i] * fcW[t*12 + i];
    out[d*2 + t] = s;
  }
}

extern "C" void kernel_launch(void* const* d_in, const int* in_sizes, int n_in,
                              void* d_out, int out_size, void* d_ws, size_t ws_size,
                              hipStream_t stream){
  const float* x    = (const float*)d_in[0];
  const float* Wihf = (const float*)d_in[1];
  const float* Whhf = (const float*)d_in[2];
  const float* bihf = (const float*)d_in[3];
  const float* bhhf = (const float*)d_in[4];
  const float* Wihb = (const float*)d_in[5];
  const float* Whhb = (const float*)d_in[6];
  const float* bihb = (const float*)d_in[7];
  const float* bhhb = (const float*)d_in[8];
  const float* encW = (const float*)d_in[9];
  const float* encB = (const float*)d_in[10];
  const float* wfcW = (const float*)d_in[11];
  const float* wfcB = (const float*)d_in[12];
  const float* fcW  = (const float*)d_in[13];
  const float* fcB  = (const float*)d_in[14];
  float* out = (float*)d_out;
  char* ws = (char*)d_ws;
  _Float16* xh = (_Float16*)(ws);                 // 66,453,504 B
  _Float16* wh = (_Float16*)(ws + 66453504);      // 22,151,168 B
  _Float16* G  = (_Float16*)(ws + 88604672);      // 25,165,824 B ; total 113,770,496
  float* H = (float*)(ws);                        // 12.6 MB, aliases dead xh after K1

  cvt_x<<<32448, 256, 0, stream>>>(x, xh);        // 6144*1352/256
  cvt_w<<<10816, 256, 0, stream>>>(Wihf, Wihb, wh);
  gemm_in<<<768, 256, 0, stream>>>(xh, wh, G, bihf, bhhf, bihb, bhhb);
  lstm_rec<<<24, 512, 0, stream>>>(Whhf, Whhb, G, H);
  epilogue<<<512, 256, 0, stream>>>(H, encW, encB, wfcW, wfcB, fcW, fcB, out);
}

// Round 2
// 1402.891 us; speedup vs baseline: 1.1923x; 1.1053x over previous
//
#include <hip/hip_runtime.h>
#include <hip/hip_bf16.h>
#include <hip/hip_fp16.h>

// Problem: bidirectional LSTM over 512 sequential steps (batch=12 lanes), then per-doc scoring.
// K0a/K0b: fp32->fp16 convert+pad, vectorized x4 (K 5400->5408). K1: MFMA fp16 GEMM (6144x5408)@(5408x2048)+bias -> G(f16),
//          m97 structure: global_load_lds width=16, linear LDS, 2 barriers/K-step.
// K2: 24 blocks (lane,dir). Whh f16 split: chunks 0..95/row in VGPRs (192 u32/thread, fits 256-cap
//     -> no spill; R1 had 232 -> spilled to scratch, 10MB spill stores + L2 reloads each step),
//     chunks 96..127/row in LDS [1024][32] u32 = 128 KB, XOR-swizzled (g^=row&7) for conflict-free b128.
//     2 barriers/step; nonlinearities hoisted pre-barrier.
// K3: per-doc epilogue fp32, exact argmax/argsort-tie semantics.
// ws: [0,66453504) x_h (later aliased by H 12.6MB) | [66453504) W_h 22.2MB | [88604672) G 25.2MB. total 113,770,496 B.

typedef _Float16 h8 __attribute__((ext_vector_type(8)));
typedef _Float16 h2 __attribute__((ext_vector_type(2)));
typedef _Float16 h4 __attribute__((ext_vector_type(4)));
typedef float f4 __attribute__((ext_vector_type(4)));

#define SEQ 512
#define NL 12
#define KIN 5400
#define KP 5408
#define NG 2048
#define MROWS 6144

__device__ __forceinline__ unsigned int pk2(float a, float b){
  h2 v; v[0] = (_Float16)a; v[1] = (_Float16)b;
  return __builtin_bit_cast(unsigned int, v);
}
__device__ __forceinline__ float dot2u(unsigned int h, unsigned int w, float acc){
  return __builtin_amdgcn_fdot2(__builtin_bit_cast(h2, h), __builtin_bit_cast(h2, w), acc, false);
}
__device__ __forceinline__ float sigm(float x){ return 1.f/(1.f + __expf(-x)); }
__device__ __forceinline__ float tanhx(float x){ return 1.f - 2.f/(__expf(2.f*x) + 1.f); }

__device__ __forceinline__ void gload16(const void* g, void* l){
  __builtin_amdgcn_global_load_lds((const __attribute__((address_space(1))) void*)g,
                                   (__attribute__((address_space(3))) void*)l, 16, 0, 0);
}

// ---------------- K0a: convert x (6144x5400 f32) -> xh (6144x5408 f16, zero pad), 4 elems/thread ----------------
__global__ void cvt_x(const float* __restrict__ x, _Float16* __restrict__ xh){
  int idx = blockIdx.x * 256 + threadIdx.x;     // < 6144*1352
  int row = idx / 1352, c4 = idx - row * 1352;
  h4 o = {};
  if (c4 < 1350){
    f4 v = *(const f4*)(x + (size_t)row * KIN + c4 * 4);
    o[0] = (_Float16)v.x; o[1] = (_Float16)v.y; o[2] = (_Float16)v.z; o[3] = (_Float16)v.w;
  }
  *(h4*)(xh + (size_t)row * KP + c4 * 4) = o;
}

// ---------------- K0b: convert [Wih_f; Wih_b] -> wh (2048x5408 f16, zero pad), 4 elems/thread ----------------
__global__ void cvt_w(const float* __restrict__ wf, const float* __restrict__ wb,
                      _Float16* __restrict__ wh){
  int idx = blockIdx.x * 256 + threadIdx.x;     // < 2048*1352
  int row = idx / 1352, c4 = idx - row * 1352;
  h4 o = {};
  if (c4 < 1350){
    const float* src = (row < 1024) ? (wf + (size_t)row * KIN) : (wb + (size_t)(row - 1024) * KIN);
    f4 v = *(const f4*)(src + c4 * 4);
    o[0] = (_Float16)v.x; o[1] = (_Float16)v.y; o[2] = (_Float16)v.z; o[3] = (_Float16)v.w;
  }
  *(h4*)(wh + (size_t)row * KP + c4 * 4) = o;
}

// ---------------- K1: G = xh @ wh^T + bias, fp16 MFMA, 128x128 tiles, global_load_lds staging ----------------
__global__ __launch_bounds__(256) void gemm_in(
    const _Float16* __restrict__ A, const _Float16* __restrict__ B, _Float16* __restrict__ G,
    const float* __restrict__ bif, const float* __restrict__ bhf,
    const float* __restrict__ bib, const float* __restrict__ bhb){
  // linear LDS tiles 128 rows x 32 k f16 (64 B/row) - dest of global_load_lds (must be linear)
  __shared__ _Float16 As[128 * 32];
  __shared__ _Float16 Bs[128 * 32];
  int tid = threadIdx.x;
  int bm = blockIdx.x % 48, bn = blockIdx.x / 48;
  int wid = tid >> 6, ln = tid & 63;
  int wm = wid & 1, wn = wid >> 1;
  int l15 = ln & 15, q = ln >> 4;
  // staging map: instr r (0/1), wave wid, lane ln -> row = r*64 + wid*16 + (ln>>2), col f16 = (ln&3)*8
  // LDS dest (HW): base + ln*16 bytes, base = r*4096 + wid*1024 (wave-uniform)
  int srow = wid * 16 + (ln >> 2);
  int scol = (ln & 3) * 8;
  const _Float16* a0 = A + (size_t)(bm * 128 + srow) * KP + scol;
  const _Float16* a1 = a0 + (size_t)64 * KP;
  const _Float16* b0 = B + (size_t)(bn * 128 + srow) * KP + scol;
  const _Float16* b1 = b0 + (size_t)64 * KP;
  char* AsB = (char*)As + wid * 1024;
  char* BsB = (char*)Bs + wid * 1024;
  f4 acc[4][4] = {};
  for (int kk = 0; kk < 169; ++kk){
    int k0 = kk * 32;
    gload16(a0 + k0, AsB);
    gload16(a1 + k0, AsB + 4096);
    gload16(b0 + k0, BsB);
    gload16(b1 + k0, BsB + 4096);
    __syncthreads();                 // drains vmcnt -> tiles in LDS
    h8 af[4], bfr[4];
    #pragma unroll
    for (int mt = 0; mt < 4; ++mt)
      af[mt] = *(const h8*)(As + (wm*64 + mt*16 + l15)*32 + q*8);
    #pragma unroll
    for (int nt = 0; nt < 4; ++nt)
      bfr[nt] = *(const h8*)(Bs + (wn*64 + nt*16 + l15)*32 + q*8);
    #pragma unroll
    for (int mt = 0; mt < 4; ++mt)
      #pragma unroll
      for (int nt = 0; nt < 4; ++nt)
        acc[mt][nt] = __builtin_amdgcn_mfma_f32_16x16x32_f16(af[mt], bfr[nt], acc[mt][nt], 0, 0, 0);
    __syncthreads();                 // all reads done before next overwrite
  }
  float bias[4];
  #pragma unroll
  for (int nt = 0; nt < 4; ++nt){
    int col = bn*128 + wn*64 + nt*16 + l15;
    bias[nt] = (col < 1024) ? (bif[col] + bhf[col]) : (bib[col-1024] + bhb[col-1024]);
  }
  #pragma unroll
  for (int mt = 0; mt < 4; ++mt)
    #pragma unroll
    for (int nt = 0; nt < 4; ++nt)
      #pragma unroll
      for (int r = 0; r < 4; ++r){
        int row = bm*128 + wm*64 + mt*16 + q*4 + r;   // C/D: row = quad*4+reg
        int col = bn*128 + wn*64 + nt*16 + l15;       //      col = lane&15
        G[(size_t)row * NG + col] = (_Float16)(acc[mt][nt][r] + bias[nt]);
      }
}

// ---------------- K2: recurrence. 24 blocks = (dir,lane). 512 thr, 2 gate rows each. ----------------
// gate layout [i(0:256) f(256:512) g(512:768) o(768:1024)]; thread t: rows t and t+512.
// t<256 owns (i_t, g_t); t+256 owns (f_t, o_t) -> pair exchange via LDS.
// Whh f16 u32-chunks: 0..95 per row in VGPRs (wa/wb = 192 u32, + ~35 working < 256 cap -> no spill),
// 96..127 per row in LDS tail[1024][32] (128 KB), 16B-granule XOR swizzle (g ^= row&7) both sides.
__global__ __launch_bounds__(512, 2) void lstm_rec(
    const float* __restrict__ Whhf, const float* __restrict__ Whhb,
    const _Float16* __restrict__ G, float* __restrict__ Hout){
  __shared__ unsigned int tail[1024][32];    // 128 KB; [row][swizzled chunk 96..127]
  __shared__ unsigned int hlds[128];         // h as 256 f16
  __shared__ float fg[256], og[256];         // hold sig(f), sig(o)
  int b = blockIdx.x;
  int dir = b / 12, lane = b - dir * 12;
  int t = threadIdx.x;
  const float* Whh = dir ? Whhb : Whhf;
  int r0 = t, r1 = t + 512;
  int sw = (t & 7) << 2;                     // swizzle (r0&7 == r1&7 == t&7)
  unsigned int wa[96], wb[96];
  #pragma unroll
  for (int c = 0; c < 128; ++c){
    float2 v0 = *(const float2*)(Whh + (size_t)r0 * 256 + 2*c);
    float2 v1 = *(const float2*)(Whh + (size_t)r1 * 256 + 2*c);
    unsigned int u0 = pk2(v0.x, v0.y);
    unsigned int u1 = pk2(v1.x, v1.y);
    if (c < 96){ wa[c] = u0; wb[c] = u1; }
    else {
      int cc = c - 96;                       // 0..31
      int g = cc >> 2, w = cc & 3;
      tail[r0][(((g << 2) ^ sw)) + w] = u0;
      tail[r1][(((g << 2) ^ sw)) + w] = u1;
    }
  }
  if (t < 128) hlds[t] = 0u;
  float cst = 0.f;
  __syncthreads();
  for (int it = 0; it < SEQ; ++it){
    int s = dir ? (SEQ - 1 - it) : it;
    const _Float16* gp = G + (size_t)(s*NL + lane) * NG + dir * 1024;
    float ga = (float)gp[r0];      // load early, used at end (overlaps dots)
    float gb = (float)gp[r1];
    float acc0 = 0.f, acc1 = 0.f;
    #pragma unroll
    for (int c4 = 0; c4 < 24; ++c4){         // VGPR-resident chunks 0..95
      uint4 hq = *(const uint4*)&hlds[c4*4];
      unsigned int ha[4] = {hq.x, hq.y, hq.z, hq.w};
      #pragma unroll
      for (int j = 0; j < 4; ++j){
        acc0 = dot2u(ha[j], wa[c4*4 + j], acc0);
        acc1 = dot2u(ha[j], wb[c4*4 + j], acc1);
      }
    }
    #pragma unroll
    for (int g = 0; g < 8; ++g){             // LDS tail chunks 96..127 (swizzled)
      uint4 hq = *(const uint4*)&hlds[96 + g*4];
      uint4 qa = *(const uint4*)&tail[r0][(g << 2) ^ sw];
      uint4 qb = *(const uint4*)&tail[r1][(g << 2) ^ sw];
      unsigned int ha[4] = {hq.x, hq.y, hq.z, hq.w};
      unsigned int qav[4] = {qa.x, qa.y, qa.z, qa.w};
      unsigned int qbv[4] = {qb.x, qb.y, qb.z, qb.w};
      #pragma unroll
      for (int j = 0; j < 4; ++j){
        acc0 = dot2u(ha[j], qav[j], acc0);
        acc1 = dot2u(ha[j], qbv[j], acc1);
      }
    }
    acc0 += ga; acc1 += gb;
    // pre-barrier nonlinearities (all 8 waves busy; shortens post-barrier chain)
    float si = 0.f, tg = 0.f;
    if (t < 256){ si = sigm(acc0); tg = tanhx(acc1); }
    else { fg[t - 256] = sigm(acc0); og[t - 256] = sigm(acc1); }
    __syncthreads();                       // gates visible; also orders hlds reads before write
    if (t < 256){
      cst = fg[t]*cst + si*tg;
      float hv = og[t]*tanhx(cst);
      ((_Float16*)hlds)[t] = (_Float16)hv;
      Hout[(size_t)(s*NL + lane)*512 + dir*256 + t] = hv;
    }
    __syncthreads();                       // new h visible before next dots
  }
}

// ---------------- K3: per-doc epilogue ----------------
__global__ __launch_bounds__(256) void epilogue(
    const float* __restrict__ H, const float* __restrict__ encW, const float* __restrict__ encB,
    const float* __restrict__ wfcW, const float* __restrict__ wfcB,
    const float* __restrict__ fcW, const float* __restrict__ fcB, float* __restrict__ out){
  __shared__ float B0[12][516];   // +4 pad -> conflict-free row access
  __shared__ float B1[12][516];
  __shared__ float encl[12][52];
  __shared__ float part[12][16];
  __shared__ float av[12], bv[12], nrm[12], simv[12], rsv[12], docv[12];
  __shared__ float Wm[12][12];
  __shared__ int corei;
  int d = blockIdx.x, t = threadIdx.x;
  const float* Hd = H + (size_t)d * NL * 512;
  for (int idx = t; idx < NL * 128; idx += 256){
    int i = idx >> 7, h4i = (idx & 127) * 4;
    *(f4*)(&B0[i][h4i]) = *(const f4*)(Hd + i*512 + h4i);
  }
  __syncthreads();
  // enc = leaky_relu(H @ enc_W.T + enc_b)
  for (int idx = t; idx < 600; idx += 256){
    int i = idx % 12, e = idx / 12;
    float s = encB[e];
    const float* w = encW + e * 512;
    for (int h = 0; h < 512; ++h) s += B0[i][h] * w[h];
    encl[i][e] = (s >= 0.f) ? s : 0.01f * s;
  }
  __syncthreads();
  if (t < 12){
    float sa = 0.f, sb = 0.f;
    for (int e = 0; e < 50; ++e){ sa += encl[t][e]*wfcW[e]; sb += encl[t][e]*wfcW[50 + e]; }
    av[t] = sa; bv[t] = sb;
  }
  __syncthreads();
  if (t < 192){                    // ||H_i||^2 partials
    int i = t >> 4, sl = t & 15;
    float s = 0.f;
    for (int h = sl*32; h < sl*32 + 32; ++h){ float v = B0[i][h]; s += v*v; }
    part[i][sl] = s;
  }
  if (t == 192){                   // core = first argmax of rowsum
    float wbv = wfcB[0];
    float best = -1e30f; int bi = 0;
    for (int i = 0; i < 12; ++i){
      float rs = 0.f;
      for (int j = 0; j < 12; ++j) if (j != i) rs += av[i] + bv[j] + wbv;
      if (rs > best){ best = rs; bi = i; }
    }
    corei = bi;
  }
  __syncthreads();
  if (t < 12){
    float s = 0.f; for (int l = 0; l < 16; ++l) s += part[t][l];
    nrm[t] = sqrtf(s) + 1e-12f;
  }
  __syncthreads();
  if (t < 192){                    // dot(H_i, H_core) partials
    int i = t >> 4, sl = t & 15, cc = corei;
    float s = 0.f;
    for (int h = sl*32; h < sl*32 + 32; ++h) s += B0[i][h] * B0[cc][h];
    part[i][sl] = s;
  }
  __syncthreads();
  if (t < 12){
    float s = 0.f; for (int l = 0; l < 16; ++l) s += part[t][l];
    simv[t] = s / (nrm[t] * nrm[corei]);
  }
  __syncthreads();
  if (t < 12){                     // stable-argsort rank of -sim
    int rk = 0; float st = simv[t];
    for (int j = 0; j < 12; ++j){
      float sj = simv[j];
      rk += (sj > st) || (sj == st && j < t);
    }
    rsv[t] = 1.f - (float)rk / 12.f;
  }
  __syncthreads();
  if (t < 144){
    int i = t / 12, j = t - (t / 12) * 12;
    Wm[i][j] = (i == j) ? 0.f : (av[i] + bv[j] + wfcB[0]) * rsv[i];
  }
  __syncthreads();
  for (int h = t; h < 512; h += 256){     // emb iter 1: B0 -> B1
    float e[12];
    #pragma unroll
    for (int j = 0; j < 12; ++j) e[j] = B0[j][h];
    #pragma unroll
    for (int i = 0; i < 12; ++i){
      float s = e[i];
      #pragma unroll
      for (int j = 0; j < 12; ++j) s += Wm[i][j] * e[j];
      B1[i][h] = s;
    }
  }
  __syncthreads();
  for (int h = t; h < 512; h += 256){     // emb iter 2: B1 -> B0
    float e[12];
    #pragma unroll
    for (int j = 0; j < 12; ++j) e[j] = B1[j][h];
    #pragma unroll
    for (int i = 0; i < 12; ++i){
      float s = e[i];
      #pragma unroll
      for (int j = 0; j < 12; ++j) s += Wm[i][j] * e[j];
      B0[i][h] = s;
    }
  }
  __syncthreads();
  if (t < 192){
    int i = t >> 4, sl = t & 15;
    float s = 0.f;
    for (int h = sl*32; h < sl*32 + 32; ++h) s += B0[i][h];
    part[i][sl] = s;
  }
  __syncthreads();
  if (t < 12){
    float s = 0.f; for (int l = 0; l < 16; ++l) s += part[t][l];
    docv[t] = s / 512.f;
  }
  __syncthreads();
  if (t < 2){
    float s = fcB[t];
    for (int i = 0; i < 12; ++i) s += docv[i] * fcW[t*12 + i];
    out[d*2 + t] = s;
  }
}

extern "C" void kernel_launch(void* const* d_in, const int* in_sizes, int n_in,
                              void* d_out, int out_size, void* d_ws, size_t ws_size,
                              hipStream_t stream){
  const float* x    = (const float*)d_in[0];
  const float* Wihf = (const float*)d_in[1];
  const float* Whhf = (const float*)d_in[2];
  const float* bihf = (const float*)d_in[3];
  const float* bhhf = (const float*)d_in[4];
  const float* Wihb = (const float*)d_in[5];
  const float* Whhb = (const float*)d_in[6];
  const float* bihb = (const float*)d_in[7];
  const float* bhhb = (const float*)d_in[8];
  const float* encW = (const float*)d_in[9];
  const float* encB = (const float*)d_in[10];
  const float* wfcW = (const float*)d_in[11];
  const float* wfcB = (const float*)d_in[12];
  const float* fcW  = (const float*)d_in[13];
  const float* fcB  = (const float*)d_in[14];
  float* out = (float*)d_out;
  char* ws = (char*)d_ws;
  _Float16* xh = (_Float16*)(ws);                 // 66,453,504 B
  _Float16* wh = (_Float16*)(ws + 66453504);      // 22,151,168 B
  _Float16* G  = (_Float16*)(ws + 88604672);      // 25,165,824 B ; total 113,770,496
  float* H = (float*)(ws);                        // 12.6 MB, aliases dead xh after K1

  cvt_x<<<32448, 256, 0, stream>>>(x, xh);        // 6144*1352/256
  cvt_w<<<10816, 256, 0, stream>>>(Wihf, Wihb, wh);
  gemm_in<<<768, 256, 0, stream>>>(xh, wh, G, bihf, bhhf, bihb, bhhb);
  lstm_rec<<<24, 512, 0, stream>>>(Whhf, Whhb, G, H);
  epilogue<<<512, 256, 0, stream>>>(H, encW, encB, wfcW, wfcB, fcW, fcB, out);
}